// Round 9
// baseline (721.427 us; speedup 1.0000x reference)
//
#include <hip/hip_runtime.h>
#include <hip/hip_bf16.h>

// B=4, S=4096, D=512, FH=2048, H=64
// outputs: progress (B*S) ++ forecast (B*S) ++ fore (B*S*D), all f32

#if __has_builtin(__builtin_amdgcn_exp2f)
__device__ __forceinline__ float EXP2(float x) { return __builtin_amdgcn_exp2f(x); }
#else
__device__ __forceinline__ float EXP2(float x) { return __expf(x * 0.6931471805599453f); }
#endif
#if __has_builtin(__builtin_amdgcn_rcpf)
__device__ __forceinline__ float RCPF(float x) { return __builtin_amdgcn_rcpf(x); }
#else
__device__ __forceinline__ float RCPF(float x) { return 1.0f / x; }
#endif

__device__ __forceinline__ float fsig(float x) { return 1.0f / (1.0f + __expf(-x)); }
__device__ __forceinline__ float ftanh(float x) { return 1.0f - 2.0f / (1.0f + __expf(2.0f * x)); }

// Single DPP add level. CTRL: 0x111/0x112/0x114/0x118 = row_shr 1/2/4/8,
// 0x142 = row_bcast15, 0x143 = row_bcast31. Full 6-level chain sums 64 lanes
// into lane 63.
template<int CTRL>
__device__ __forceinline__ float dppadd(float x) {
    return x + __int_as_float(__builtin_amdgcn_update_dpp(
        0, __float_as_int(x), CTRL, 0xf, 0xf, true));
}
__device__ __forceinline__ float dpp_sum64_lane63(float x) {
    x = dppadd<0x111>(x); x = dppadd<0x112>(x); x = dppadd<0x114>(x);
    x = dppadd<0x118>(x); x = dppadd<0x142>(x); x = dppadd<0x143>(x);
    return x;
}
__device__ __forceinline__ float readlane63(float x) {
    return __int_as_float(__builtin_amdgcn_readlane(__float_as_int(x), 63));
}

constexpr float L2E2 = 2.8853900817779268f;  // 2*log2(e)

// ---------------------------------------------------------------------------
// 64x64 f32 tile core (BK=16)
// ---------------------------------------------------------------------------
template<bool BT>
__device__ void gemm_tile_acc(const float* __restrict__ A, const float* __restrict__ B,
                              int K, int N, int bm, int bn,
                              float (* __restrict__ As)[68], float (* __restrict__ Bs)[68],
                              float acc[4][4])
{
    const int tid = threadIdx.x;
    const int tx = tid & 15, ty = tid >> 4;
    for (int k0 = 0; k0 < K; k0 += 16) {
        {
            const int r = tid >> 2, cc = (tid & 3) * 4;
            const float4 av = *reinterpret_cast<const float4*>(
                &A[(size_t)(bm + r) * K + k0 + cc]);
            As[cc + 0][r] = av.x; As[cc + 1][r] = av.y;
            As[cc + 2][r] = av.z; As[cc + 3][r] = av.w;
        }
        if (BT) {
            const int r = tid >> 2, cc = (tid & 3) * 4;
            const float4 bv = *reinterpret_cast<const float4*>(
                &B[(size_t)(bn + r) * K + k0 + cc]);
            Bs[cc + 0][r] = bv.x; Bs[cc + 1][r] = bv.y;
            Bs[cc + 2][r] = bv.z; Bs[cc + 3][r] = bv.w;
        } else {
            const int r = tid >> 4, cc = (tid & 15) * 4;
            const float4 bv = *reinterpret_cast<const float4*>(
                &B[(size_t)(k0 + r) * N + bn + cc]);
            Bs[r][cc + 0] = bv.x; Bs[r][cc + 1] = bv.y;
            Bs[r][cc + 2] = bv.z; Bs[r][cc + 3] = bv.w;
        }
        __syncthreads();
        #pragma unroll
        for (int k = 0; k < 16; ++k) {
            float a[4], b[4];
            #pragma unroll
            for (int i = 0; i < 4; ++i) a[i] = As[k][ty * 4 + i];
            #pragma unroll
            for (int j = 0; j < 4; ++j) b[j] = Bs[k][tx * 4 + j];
            #pragma unroll
            for (int i = 0; i < 4; ++i)
                #pragma unroll
                for (int j = 0; j < 4; ++j)
                    acc[i][j] = fmaf(a[i], b[j], acc[i][j]);
        }
        __syncthreads();
    }
}

// ---------------------------------------------------------------------------
// prep: blocks [0,64) Weff = W2@W1 ; [64,72) beff = W2@b1+b2 ; [72,328) Gx
// Gx epilogue applies the h-free ACTIVATION directly:
//   cols i,f,o: sigmoid(G + bih + bhh);  col g: tanh(G + bih + bhh)
// ---------------------------------------------------------------------------
__global__ __launch_bounds__(256) void prep_kernel(
    const float* __restrict__ x, const float* __restrict__ W1,
    const float* __restrict__ b1, const float* __restrict__ W2,
    const float* __restrict__ b2, const float* __restrict__ Wih,
    const float* __restrict__ bih, const float* __restrict__ bhh,
    float* __restrict__ Weff, float* __restrict__ beff, float* __restrict__ Gx)
{
    __shared__ float As[16][68], Bs[16][68];
    const int bid = blockIdx.x;
    const int tx = threadIdx.x & 15, ty = threadIdx.x >> 4;

    if (bid < 64) {
        const int bm = (bid >> 3) * 64, bn = (bid & 7) * 64;
        float acc[4][4] = {};
        gemm_tile_acc<false>(W2, W1, 2048, 512, bm, bn, As, Bs, acc);
        #pragma unroll
        for (int i = 0; i < 4; ++i)
            #pragma unroll
            for (int j = 0; j < 4; ++j)
                Weff[(size_t)(bm + ty * 4 + i) * 512 + bn + tx * 4 + j] = acc[i][j];
    } else if (bid < 72) {
        const int w = threadIdx.x >> 6, j = threadIdx.x & 63;
        const int base = (bid - 64) * 64 + w * 16;
        for (int o = 0; o < 16; ++o) {
            const int i = base + o;
            float s = 0.0f;
            #pragma unroll
            for (int m = 0; m < 32; ++m)
                s = fmaf(W2[(size_t)i * 2048 + j + 64 * m], b1[j + 64 * m], s);
            s = dpp_sum64_lane63(s);
            if (j == 63) beff[i] = s + b2[i];
        }
    } else {
        const int b = bid - 72;
        const int bm = (b >> 2) * 64, bn = (b & 3) * 64;
        float acc[4][4] = {};
        gemm_tile_acc<true>(x, Wih, 512, 256, bm, bn, As, Bs, acc);
        #pragma unroll
        for (int i = 0; i < 4; ++i)
            #pragma unroll
            for (int j = 0; j < 4; ++j) {
                const int col = bn + tx * 4 + j;
                const float a = acc[i][j] + bih[col] + bhh[col];
                const float v = ((col >> 6) == 2) ? ftanh(a) : fsig(a);
                Gx[(size_t)(bm + ty * 4 + i) * 256 + col] = v;
            }
    }
}

// ---------------------------------------------------------------------------
// wg: blocks [0,32) Wg = Wih @ Weff; block 32: bf2 = Wih @ beff
// ---------------------------------------------------------------------------
__global__ __launch_bounds__(256) void wg_kernel(
    const float* __restrict__ Wih, const float* __restrict__ Weff,
    const float* __restrict__ beff, float* __restrict__ Wg, float* __restrict__ bf2)
{
    __shared__ float As[16][68], Bs[16][68];
    const int bid = blockIdx.x;
    if (bid < 32) {
        const int bm = (bid >> 3) * 64, bn = (bid & 7) * 64;
        const int tx = threadIdx.x & 15, ty = threadIdx.x >> 4;
        float acc[4][4] = {};
        gemm_tile_acc<false>(Wih, Weff, 512, 512, bm, bn, As, Bs, acc);
        #pragma unroll
        for (int i = 0; i < 4; ++i)
            #pragma unroll
            for (int j = 0; j < 4; ++j)
                Wg[(size_t)(bm + ty * 4 + i) * 512 + bn + tx * 4 + j] = acc[i][j];
    } else {
        const int w = threadIdx.x >> 6, j = threadIdx.x & 63;
        for (int o = 0; o < 64; ++o) {
            const int i = w * 64 + o;
            float s = 0.0f;
            #pragma unroll
            for (int m = 0; m < 8; ++m)
                s = fmaf(Wih[(size_t)i * 512 + j + 64 * m], beff[j + 64 * m], s);
            s = dpp_sum64_lane63(s);
            if (j == 63) bf2[i] = s;
        }
    }
}

// ---------------------------------------------------------------------------
// scanfore: block 0 = LDS-staged scan with PIPELINED cross-lane reduces.
//   Per-lane hv(t) ~ P0 + P1*h(t-1) where P0,P1 depend only on c(t-1) ->
//   reduce(t) overlaps reduce(t-1): each iter runs DPP levels 1-3 of step t
//   and levels 4-6 of step t-1 (2-deep chain pipeline, halves latency floor).
//   c keeps the full lane-local quadratic update (exact at h=0 center).
// blocks [1,2049) fore = x @ Weff^T + beff; [2049,2305) Gf = x @ Wg^T.
// ---------------------------------------------------------------------------
__global__ __launch_bounds__(256) void scanfore_kernel(
    const float* __restrict__ x, const float* __restrict__ Weff,
    const float* __restrict__ beff, const float* __restrict__ Gx,
    const float* __restrict__ Wg,
    const float* __restrict__ Whh, const float* __restrict__ bih,
    const float* __restrict__ bhh, const float* __restrict__ Whr,
    float* __restrict__ c_hist, float* __restrict__ p,
    float* __restrict__ fore, float* __restrict__ Gf)
{
    __shared__ __align__(16) float smem[16384];     // 64 KB: gbufA | gbufB
    constexpr int S = 4096, CH = 32, NCH = S / CH;  // 128 chunks

    if (blockIdx.x == 0) {
        const int tid = threadIdx.x;
        float* gbufA = smem;
        float* gbufB = smem + 8192;

        // prologue: all 256 threads load chunk 0 into gbufA
        {
            const float4* src = reinterpret_cast<const float4*>(Gx);
            float4* dst = reinterpret_cast<float4*>(gbufA);
            #pragma unroll
            for (int u = 0; u < 8; ++u) dst[tid + u * 256] = src[tid + u * 256];
        }
        __syncthreads();

        if (tid >= 64) {
            // ---- loader waves ----
            const int lt = tid - 64;  // 0..191
            auto fill = [&](float* dstf, int chunk) {
                const float4* src = reinterpret_cast<const float4*>(
                    Gx + (size_t)chunk * CH * 256);
                float4* dst = reinterpret_cast<float4*>(dstf);
                float4 tmp[11];
                #pragma unroll
                for (int u = 0; u < 11; ++u) {
                    const int idx = lt + u * 192;
                    if (idx < 2048) tmp[u] = src[idx];
                }
                #pragma unroll
                for (int u = 0; u < 11; ++u) {
                    const int idx = lt + u * 192;
                    if (idx < 2048) dst[idx] = tmp[u];
                }
            };
            fill(gbufB, 1);
            for (int cc = 0; cc < NCH; ++cc) {
                __syncthreads();
                if (cc + 2 < NCH) fill((cc & 1) ? gbufB : gbufA, cc + 2);
            }
            return;
        }

        // ---- wave 0: the sequential scan ----
        __builtin_amdgcn_s_setprio(3);
        const int j = tid;

        const float wi = Whh[j],       wf = Whh[64 + j];
        const float wg = Whh[128 + j], wo = Whh[192 + j];
        const float whr = Whr[j];

        float h, c;
        float r0[8], r1[8], r2[8], r3[8];
        float p0, p1, s0, s1, c0_t, D1_t, D2_t;

        #pragma unroll
        for (int q = 0; q < 8; ++q) {
            const float* Bp = gbufA + q * 256 + j;
            r0[q] = Bp[0]; r1[q] = Bp[64]; r2[q] = Bp[128]; r3[q] = Bp[192];
        }

// From ring slot Q_ and cell value C_ (= c(t-1)), produce P0/P1 (coeffs of
// hv(t) in h(t-1)) and c0/D1/D2 (coeffs of c(t) in h(t-1)). Exact at h=0.
#define SHADOW_CALC(Q_, C_, P0o, P1o, C0o, D1o, D2o) {                        \
        const float Ai=r0[Q_], Af=r1[Q_], Ag=r2[Q_], Ao=r3[Q_];               \
        const float AiAg = Ai*Ag;                                             \
        const float ai1 = fmaf(-Ai,Ai,Ai), af1 = fmaf(-Af,Af,Af);             \
        const float ag1 = fmaf(-Ag,Ag,1.0f), ao1 = fmaf(-Ao,Ao,Ao);           \
        const float I1=ai1*wi, F1=af1*wf, G1=ag1*wg, O1=ao1*wo;               \
        const float I2=(I1*wi)*(0.5f-Ai), F2=(F1*wf)*(0.5f-Af);               \
        const float G2=-(Ag*G1)*wg;                                           \
        const float K1=fmaf(I1,Ag, Ai*G1);                                    \
        const float K2=fmaf(I2,Ag, fmaf(I1,G1, Ai*G2));                       \
        const float Oq0=Ao*whr, Oq1=O1*whr;                                   \
        C0o = fmaf(Af,(C_),AiAg);                                             \
        const float t0_ = fmaf(-2.0f, RCPF(1.0f + EXP2(C0o*L2E2)), 1.0f);     \
        const float T1_ = fmaf(-t0_,t0_,1.0f);                                \
        D1o = fmaf(F1,(C_),K1); D2o = fmaf(F2,(C_),K2);                       \
        P0o = t0_*Oq0;                                                        \
        P1o = fmaf(T1_*D1o, Oq0, t0_*Oq1);                                    \
    }

        // ---- step 0 (h(-1)=0, c(-1)=0): exact ----
        {
            const float Ai = r0[0], Ag = r2[0], Ao = r3[0];
            const float c0 = Ai * Ag;
            const float t0 = fmaf(-2.0f, RCPF(1.0f + EXP2(c0 * L2E2)), 1.0f);
            float P0 = t0 * (Ao * whr);
            P0 = dpp_sum64_lane63(P0);
            h = readlane63(P0);
            c = c0;
            c_hist[j] = c;
            if (j == 0) p[0] = h;
        }
        // ---- prime: shadow(1) -> half-reduce; c(1); shadow(2) ----
        {
            float q0, q1, c01, D11, D21;
            SHADOW_CALC(1, c, q0, q1, c01, D11, D21);
            s0 = dppadd<0x114>(dppadd<0x112>(dppadd<0x111>(q0)));
            s1 = dppadd<0x114>(dppadd<0x112>(dppadd<0x111>(q1)));
            c = fmaf(fmaf(D21, h, D11), h, c01);            // c(1)
            c_hist[64 + j] = c;
            SHADOW_CALC(2, c, p0, p1, c0_t, D1_t, D2_t);
            // refill slots 0,1 <- steps 8,9
            const float* B8 = gbufA + 8 * 256 + j;
            const float* B9 = gbufA + 9 * 256 + j;
            r0[0]=B8[0]; r1[0]=B8[64]; r2[0]=B8[128]; r3[0]=B8[192];
            r0[1]=B9[0]; r1[1]=B9[64]; r2[1]=B9[128]; r3[1]=B9[192];
        }

// ITER(t): completes reduce(t-1) -> h(t-1); starts reduce(t); computes c(t);
// shadow(t+1). RP_: ring refill pointer for step t+8 (slot t&7).
#define ITER_BODY(CC_, S_, RP_, DOREF_) {                                     \
        const int T_ = (CC_)*CH + (S_);                                       \
        float x0 = dppadd<0x111>(p0), x1 = dppadd<0x111>(p1);                 \
        s0 = dppadd<0x118>(s0); s1 = dppadd<0x118>(s1);                       \
        if (DOREF_) { const float* Bp_ = (RP_); const int qr_ = (S_)&7;       \
            r0[qr_]=Bp_[0]; r1[qr_]=Bp_[64];                                  \
            r2[qr_]=Bp_[128]; r3[qr_]=Bp_[192]; }                             \
        x0 = dppadd<0x112>(x0); x1 = dppadd<0x112>(x1);                       \
        s0 = dppadd<0x142>(s0); s1 = dppadd<0x142>(s1);                       \
        x0 = dppadd<0x114>(x0); x1 = dppadd<0x114>(x1);                       \
        s0 = dppadd<0x143>(s0); s1 = dppadd<0x143>(s1);                       \
        const float A0_ = readlane63(s0), A1_ = readlane63(s1);               \
        h = A1_*h + A0_;                       /* h(t-1); 1-SGPR per op */    \
        if (j == 0) p[T_-1] = h;                                              \
        c = fmaf(fmaf(D2_t, h, D1_t), h, c0_t);             /* c(t) */        \
        c_hist[(size_t)T_*64 + j] = c;                                        \
        const int q1_ = ((S_)+1)&7;                                           \
        SHADOW_CALC(q1_, c, p0, p1, c0_t, D1_t, D2_t);      /* step t+1 */    \
        s0 = x0; s1 = x1;                                                     \
    }

        // ---- chunk 0: t = 2..31 ----
        {
            #pragma unroll
            for (int s_ = 2; s_ < 24; ++s_)
                ITER_BODY(0, s_, gbufA + (s_ + 8) * 256 + j, true)
            __syncthreads();
            #pragma unroll
            for (int s_ = 24; s_ < 32; ++s_)
                ITER_BODY(0, s_, gbufB + (s_ - 24) * 256 + j, true)
        }
        // ---- chunks 1..NCH-1 ----
        for (int cc = 1; cc < NCH; ++cc) {
            const float* bufC = (cc & 1) ? gbufB : gbufA;
            const float* bufN = (cc & 1) ? gbufA : gbufB;
            #pragma unroll
            for (int s_ = 0; s_ < 24; ++s_)
                ITER_BODY(cc, s_, bufC + (s_ + 8) * 256 + j, true)
            __syncthreads();
            if (cc + 1 < NCH) {
                #pragma unroll
                for (int s_ = 24; s_ < 32; ++s_)
                    ITER_BODY(cc, s_, bufN + (s_ - 24) * 256 + j, true)
            } else {
                #pragma unroll
                for (int s_ = 24; s_ < 32; ++s_)
                    ITER_BODY(cc, s_, gbufA, false)
            }
        }
        // ---- epilogue: finish reduce(4095) -> h(4095) ----
        {
            s0 = dppadd<0x143>(dppadd<0x142>(dppadd<0x118>(s0)));
            s1 = dppadd<0x143>(dppadd<0x142>(dppadd<0x118>(s1)));
            const float A0_ = readlane63(s0), A1_ = readlane63(s1);
            h = A1_*h + A0_;
            if (j == 0) p[S - 1] = h;
        }
#undef ITER_BODY
#undef SHADOW_CALC
        return;
    }

    float (*As)[68] = reinterpret_cast<float(*)[68]>(smem);
    float (*Bs)[68] = reinterpret_cast<float(*)[68]>(smem + 16 * 68);
    const int bid = blockIdx.x - 1;
    const int tx = threadIdx.x & 15, ty = threadIdx.x >> 4;
    if (bid < 2048) {                      // fore tiles: 256 x 8
        const int bm = (bid >> 3) * 64, bn = (bid & 7) * 64;
        float acc[4][4] = {};
        gemm_tile_acc<true>(x, Weff, 512, 512, bm, bn, As, Bs, acc);
        #pragma unroll
        for (int i = 0; i < 4; ++i)
            #pragma unroll
            for (int j = 0; j < 4; ++j)
                fore[(size_t)(bm + ty * 4 + i) * 512 + bn + tx * 4 + j] =
                    acc[i][j] + beff[bn + tx * 4 + j];
    } else {                               // Gf tiles: 64 x 4
        const int t = bid - 2048;
        const int bm = (t >> 2) * 64, bn = (t & 3) * 64;
        float acc[4][4] = {};
        gemm_tile_acc<true>(x, Wg, 512, 256, bm, bn, As, Bs, acc);
        #pragma unroll
        for (int i = 0; i < 4; ++i)
            #pragma unroll
            for (int j = 0; j < 4; ++j)
                Gf[(size_t)(bm + ty * 4 + i) * 256 + bn + tx * 4 + j] = acc[i][j];
    }
}

// ---------------------------------------------------------------------------
// finish: blocks [0,64) forecast cells (exact math; + forecast broadcast);
//         blocks [64,128) progress broadcast
// ---------------------------------------------------------------------------
__global__ __launch_bounds__(256) void finish_kernel(
    const float* __restrict__ Gf, const float* __restrict__ bf2,
    const float* __restrict__ Whh, const float* __restrict__ bih,
    const float* __restrict__ bhh, const float* __restrict__ Whr,
    const float* __restrict__ c_hist, const float* __restrict__ p,
    float* __restrict__ out)
{
    constexpr int S = 4096, BS = 4 * 4096;
    const int bid = blockIdx.x;
    if (bid < 64) {
        const int w = threadIdx.x >> 6, j = threadIdx.x & 63;
        const float bi0 = bf2[j]       + bih[j]       + bhh[j];
        const float bi1 = bf2[64 + j]  + bih[64 + j]  + bhh[64 + j];
        const float bi2 = bf2[128 + j] + bih[128 + j] + bhh[128 + j];
        const float bi3 = bf2[192 + j] + bih[192 + j] + bhh[192 + j];
        for (int o = 0; o < 16; ++o) {
            const int t = bid * 64 + w * 16 + o;
            const float h2 = p[t];
            const float c2 = c_hist[(size_t)t * 64 + j];
            const float* G = Gf + (size_t)t * 256;
            const float gi = G[j]       + bi0 + Whh[j] * h2;
            const float gf = G[64 + j]  + bi1 + Whh[64 + j] * h2;
            const float gg = G[128 + j] + bi2 + Whh[128 + j] * h2;
            const float go = G[192 + j] + bi3 + Whh[192 + j] * h2;
            const float cf = fsig(gf) * c2 + fsig(gi) * ftanh(gg);
            float hv = fsig(go) * ftanh(cf) * Whr[j];
            hv = dpp_sum64_lane63(hv);
            if (j == 63) {
                out[BS + 0 * S + t] = hv;
                out[BS + 1 * S + t] = hv;
                out[BS + 2 * S + t] = hv;
                out[BS + 3 * S + t] = hv;
            }
        }
    } else {
        const int i = (bid - 64) * 256 + threadIdx.x;
        out[i] = p[i & (S - 1)];
    }
}

extern "C" void kernel_launch(void* const* d_in, const int* in_sizes, int n_in,
                              void* d_out, int out_size, void* d_ws, size_t ws_size,
                              hipStream_t stream) {
    const float* x   = (const float*)d_in[0];
    const float* W1  = (const float*)d_in[1];
    const float* b1  = (const float*)d_in[2];
    const float* W2  = (const float*)d_in[3];
    const float* b2  = (const float*)d_in[4];
    const float* Wih = (const float*)d_in[5];
    const float* Whh = (const float*)d_in[6];
    const float* bih = (const float*)d_in[7];
    const float* bhh = (const float*)d_in[8];
    const float* Whr = (const float*)d_in[9];
    float* out = (float*)d_out;

    constexpr int Bb = 4, S = 4096;
    const int M = Bb * S; // 16384

    float* ws     = (float*)d_ws;
    float* Weff   = ws;                       // 512*512
    float* beff   = Weff + 512 * 512;         // 512
    float* Gx     = beff + 512;               // 4096*256 (h-free activations)
    float* Gf     = Gx + S * 256;             // 4096*256
    float* c_hist = Gf + S * 256;             // 4096*64
    float* p      = c_hist + S * 64;          // 4096
    float* Wg     = p + S;                    // 256*512
    float* bf2    = Wg + 256 * 512;           // 256

    float* fore = out + 2 * M;                // (16384,512) region of d_out

    // 1) Weff/beff/Gx
    prep_kernel<<<328, 256, 0, stream>>>(
        x, W1, b1, W2, b2, Wih, bih, bhh, Weff, beff, Gx);

    // 2) Wg = Wih@Weff, bf2 = Wih@beff
    wg_kernel<<<33, 256, 0, stream>>>(Wih, Weff, beff, Wg, bf2);

    // 3) scan (block 0, pipelined reduces) || fore GEMM || Gf GEMM
    scanfore_kernel<<<2305, 256, 0, stream>>>(
        x, Weff, beff, Gx, Wg, Whh, bih, bhh, Whr, c_hist, p, fore, Gf);

    // 4) forecast cells + output broadcasts
    finish_kernel<<<128, 256, 0, stream>>>(
        Gf, bf2, Whh, bih, bhh, Whr, c_hist, p, out);
}

// Round 10
// 438.852 us; speedup vs baseline: 1.6439x; 1.6439x over previous
//
#include <hip/hip_runtime.h>
#include <hip/hip_bf16.h>

// B=4, S=4096, D=512, FH=2048, H=64
// outputs: progress (B*S) ++ forecast (B*S) ++ fore (B*S*D), all f32
//
// Structure (parallel-in-time fixed point, K=3 iterations):
//   prep:  Weff = W2@W1, beff = W2@b1+b2, Gx = raw gate pre-activations
//   wg:    Wg = Wih@Weff, bf2 = Wih@beff
//   6 x fused: {phase A | phase B} of fixed-point iteration + fore/Gf tiles
//   finish: forecast cells + broadcasts

#if __has_builtin(__builtin_amdgcn_exp2f)
__device__ __forceinline__ float EXP2(float x) { return __builtin_amdgcn_exp2f(x); }
#else
__device__ __forceinline__ float EXP2(float x) { return __expf(x * 0.6931471805599453f); }
#endif
#if __has_builtin(__builtin_amdgcn_rcpf)
__device__ __forceinline__ float RCPF(float x) { return __builtin_amdgcn_rcpf(x); }
#else
__device__ __forceinline__ float RCPF(float x) { return 1.0f / x; }
#endif

constexpr float L2E  = 1.4426950408889634f;
constexpr float L2E2 = 2.8853900817779268f;

__device__ __forceinline__ float fsig(float x) { return 1.0f / (1.0f + __expf(-x)); }
__device__ __forceinline__ float ftanh(float x) { return 1.0f - 2.0f / (1.0f + __expf(2.0f * x)); }
__device__ __forceinline__ float sig_f(float x)  { return RCPF(1.0f + EXP2(-L2E * x)); }
__device__ __forceinline__ float tanh_f(float x) { return fmaf(-2.0f, RCPF(1.0f + EXP2(L2E2 * x)), 1.0f); }

template<int CTRL>
__device__ __forceinline__ float dppadd(float x) {
    return x + __int_as_float(__builtin_amdgcn_update_dpp(
        0, __float_as_int(x), CTRL, 0xf, 0xf, true));
}
__device__ __forceinline__ float dpp_sum64_lane63(float x) {
    x = dppadd<0x111>(x); x = dppadd<0x112>(x); x = dppadd<0x114>(x);
    x = dppadd<0x118>(x); x = dppadd<0x142>(x); x = dppadd<0x143>(x);
    return x;
}
__device__ __forceinline__ float readlane63(float x) {
    return __int_as_float(__builtin_amdgcn_readlane(__float_as_int(x), 63));
}
__device__ __forceinline__ float readlane_s(float x, int s) {
    return __int_as_float(__builtin_amdgcn_readlane(__float_as_int(x), s));
}

// ---------------------------------------------------------------------------
// 64x64 f32 tile core (BK=16)
// ---------------------------------------------------------------------------
template<bool BT>
__device__ void gemm_tile_acc(const float* __restrict__ A, const float* __restrict__ B,
                              int K, int N, int bm, int bn,
                              float (* __restrict__ As)[68], float (* __restrict__ Bs)[68],
                              float acc[4][4])
{
    const int tid = threadIdx.x;
    const int tx = tid & 15, ty = tid >> 4;
    for (int k0 = 0; k0 < K; k0 += 16) {
        {
            const int r = tid >> 2, cc = (tid & 3) * 4;
            const float4 av = *reinterpret_cast<const float4*>(
                &A[(size_t)(bm + r) * K + k0 + cc]);
            As[cc + 0][r] = av.x; As[cc + 1][r] = av.y;
            As[cc + 2][r] = av.z; As[cc + 3][r] = av.w;
        }
        if (BT) {
            const int r = tid >> 2, cc = (tid & 3) * 4;
            const float4 bv = *reinterpret_cast<const float4*>(
                &B[(size_t)(bn + r) * K + k0 + cc]);
            Bs[cc + 0][r] = bv.x; Bs[cc + 1][r] = bv.y;
            Bs[cc + 2][r] = bv.z; Bs[cc + 3][r] = bv.w;
        } else {
            const int r = tid >> 4, cc = (tid & 15) * 4;
            const float4 bv = *reinterpret_cast<const float4*>(
                &B[(size_t)(k0 + r) * N + bn + cc]);
            Bs[r][cc + 0] = bv.x; Bs[r][cc + 1] = bv.y;
            Bs[r][cc + 2] = bv.z; Bs[r][cc + 3] = bv.w;
        }
        __syncthreads();
        #pragma unroll
        for (int k = 0; k < 16; ++k) {
            float a[4], b[4];
            #pragma unroll
            for (int i = 0; i < 4; ++i) a[i] = As[k][ty * 4 + i];
            #pragma unroll
            for (int j = 0; j < 4; ++j) b[j] = Bs[k][tx * 4 + j];
            #pragma unroll
            for (int i = 0; i < 4; ++i)
                #pragma unroll
                for (int j = 0; j < 4; ++j)
                    acc[i][j] = fmaf(a[i], b[j], acc[i][j]);
        }
        __syncthreads();
    }
}

// ---------------------------------------------------------------------------
// prep: blocks [0,64) Weff = W2@W1 ; [64,72) beff ; [72,328) Gx RAW
//   Gx[t][col] = (x[t] . Wih[col]) + bih[col] + bhh[col]   (no activation)
// ---------------------------------------------------------------------------
__global__ __launch_bounds__(256) void prep_kernel(
    const float* __restrict__ x, const float* __restrict__ W1,
    const float* __restrict__ b1, const float* __restrict__ W2,
    const float* __restrict__ b2, const float* __restrict__ Wih,
    const float* __restrict__ bih, const float* __restrict__ bhh,
    float* __restrict__ Weff, float* __restrict__ beff, float* __restrict__ Gx)
{
    __shared__ float As[16][68], Bs[16][68];
    const int bid = blockIdx.x;
    const int tx = threadIdx.x & 15, ty = threadIdx.x >> 4;

    if (bid < 64) {
        const int bm = (bid >> 3) * 64, bn = (bid & 7) * 64;
        float acc[4][4] = {};
        gemm_tile_acc<false>(W2, W1, 2048, 512, bm, bn, As, Bs, acc);
        #pragma unroll
        for (int i = 0; i < 4; ++i)
            #pragma unroll
            for (int j = 0; j < 4; ++j)
                Weff[(size_t)(bm + ty * 4 + i) * 512 + bn + tx * 4 + j] = acc[i][j];
    } else if (bid < 72) {
        const int w = threadIdx.x >> 6, j = threadIdx.x & 63;
        const int base = (bid - 64) * 64 + w * 16;
        for (int o = 0; o < 16; ++o) {
            const int i = base + o;
            float s = 0.0f;
            #pragma unroll
            for (int m = 0; m < 32; ++m)
                s = fmaf(W2[(size_t)i * 2048 + j + 64 * m], b1[j + 64 * m], s);
            s = dpp_sum64_lane63(s);
            if (j == 63) beff[i] = s + b2[i];
        }
    } else {
        const int b = bid - 72;
        const int bm = (b >> 2) * 64, bn = (b & 3) * 64;
        float acc[4][4] = {};
        gemm_tile_acc<true>(x, Wih, 512, 256, bm, bn, As, Bs, acc);
        #pragma unroll
        for (int i = 0; i < 4; ++i)
            #pragma unroll
            for (int j = 0; j < 4; ++j) {
                const int col = bn + tx * 4 + j;
                Gx[(size_t)(bm + ty * 4 + i) * 256 + col] =
                    acc[i][j] + bih[col] + bhh[col];
            }
    }
}

// ---------------------------------------------------------------------------
// wg: blocks [0,32) Wg = Wih @ Weff; block 32: bf2 = Wih @ beff
// ---------------------------------------------------------------------------
__global__ __launch_bounds__(256) void wg_kernel(
    const float* __restrict__ Wih, const float* __restrict__ Weff,
    const float* __restrict__ beff, float* __restrict__ Wg, float* __restrict__ bf2)
{
    __shared__ float As[16][68], Bs[16][68];
    const int bid = blockIdx.x;
    if (bid < 32) {
        const int bm = (bid >> 3) * 64, bn = (bid & 7) * 64;
        const int tx = threadIdx.x & 15, ty = threadIdx.x >> 4;
        float acc[4][4] = {};
        gemm_tile_acc<false>(Wih, Weff, 512, 512, bm, bn, As, Bs, acc);
        #pragma unroll
        for (int i = 0; i < 4; ++i)
            #pragma unroll
            for (int j = 0; j < 4; ++j)
                Wg[(size_t)(bm + ty * 4 + i) * 512 + bn + tx * 4 + j] = acc[i][j];
    } else {
        const int w = threadIdx.x >> 6, j = threadIdx.x & 63;
        for (int o = 0; o < 64; ++o) {
            const int i = w * 64 + o;
            float s = 0.0f;
            #pragma unroll
            for (int m = 0; m < 8; ++m)
                s = fmaf(Wih[(size_t)i * 512 + j + 64 * m], beff[j + 64 * m], s);
            s = dpp_sum64_lane63(s);
            if (j == 63) bf2[i] = s;
        }
    }
}

// ---------------------------------------------------------------------------
// fused: blocks [0,16) = fixed-point phase work (64 chunk-waves);
//        blocks [16,16+fore_cnt) = fore tiles [fore_base ...);
//        remaining blocks = Gf tiles.
// phase==0 (A): per (chunk,j) compose c-recurrence over the chunk:
//   (P,Q) with c_end = P*c_start + Q, gates evaluated at h = hprev.
// phase==1 (B): chunk-start c via prefix over (P,Q); re-walk chunk,
//   c(t,j), h(t) = DPP-reduce(Whr_j * sig(o)*tanh(c)); store h -> hnext.
//   last: also store c_hist and p.
// ---------------------------------------------------------------------------
__global__ __launch_bounds__(256) void fused_kernel(
    int phase, int first, int last,
    const float* __restrict__ x, const float* __restrict__ Weff,
    const float* __restrict__ beff, const float* __restrict__ Wg,
    const float* __restrict__ Gx,
    const float* __restrict__ Whh, const float* __restrict__ Whr,
    const float* __restrict__ hprev, float* __restrict__ hnext,
    float* __restrict__ P, float* __restrict__ Q,
    float* __restrict__ c_hist, float* __restrict__ p,
    float* __restrict__ fore, float* __restrict__ Gf,
    int fore_base, int fore_cnt)
{
    __shared__ float As[16][68], Bs[16][68];

    if (blockIdx.x < 16) {
        const int chunk = blockIdx.x * 4 + (threadIdx.x >> 6);  // 0..63
        const int j = threadIdx.x & 63;
        const float wi = Whh[j], wf = Whh[64 + j];
        const float wg2 = Whh[128 + j], wo = Whh[192 + j];
        const float* ab = Gx + (size_t)chunk * 64 * 256 + j;

        // preload this chunk's h(t-1) values: lane l -> hprev[chunk*64-1+l]
        float hp = 0.0f;
        if (!first) {
            const int idx = chunk * 64 - 1 + j;
            hp = (idx >= 0) ? hprev[idx] : 0.0f;
        }

        if (phase == 0) {
            float Pv = 1.0f, Qv = 0.0f;
            #pragma unroll 8
            for (int s = 0; s < 64; ++s) {
                const float hs = first ? 0.0f : readlane_s(hp, s);
                const float ai = ab[s * 256]       + wi  * hs;
                const float af = ab[s * 256 + 64]  + wf  * hs;
                const float ag = ab[s * 256 + 128] + wg2 * hs;
                const float si = sig_f(ai);
                const float sf = sig_f(af);
                const float tg = tanh_f(ag);
                Pv = sf * Pv;
                Qv = fmaf(sf, Qv, si * tg);
            }
            P[chunk * 64 + j] = Pv;
            Q[chunk * 64 + j] = Qv;
        } else {
            const float whr = Whr[j];
            // chunk-start c: fold preceding chunk summaries (per lane j)
            float c = 0.0f;
            #pragma unroll 8
            for (int m = 0; m < chunk; ++m)
                c = fmaf(P[m * 64 + j], c, Q[m * 64 + j]);
            float vp = 0.0f;
            #pragma unroll 4
            for (int s = 0; s < 64; ++s) {
                const float hs = first ? 0.0f : readlane_s(hp, s);
                const float ai = ab[s * 256]       + wi  * hs;
                const float af = ab[s * 256 + 64]  + wf  * hs;
                const float ag = ab[s * 256 + 128] + wg2 * hs;
                const float ao = ab[s * 256 + 192] + wo  * hs;
                const float si = sig_f(ai);
                const float sf = sig_f(af);
                const float tg = tanh_f(ag);
                const float so = sig_f(ao);
                c = fmaf(sf, c, si * tg);
                if (last) c_hist[(size_t)(chunk * 64 + s) * 64 + j] = c;
                const float tc = tanh_f(c);
                float hv = tc * (so * whr);
                hv = dpp_sum64_lane63(hv);
                const float hn = readlane63(hv);
                vp = (j == s) ? hn : vp;
            }
            hnext[chunk * 64 + j] = vp;
            if (last) p[chunk * 64 + j] = vp;
        }
        return;
    }

    const int bt = blockIdx.x - 16;
    const int tx = threadIdx.x & 15, ty = threadIdx.x >> 4;
    if (bt < fore_cnt) {                   // fore tile: 2048 total = 256 x 8
        const int tile = fore_base + bt;
        const int bm = (tile >> 3) * 64, bn = (tile & 7) * 64;
        float acc[4][4] = {};
        gemm_tile_acc<true>(x, Weff, 512, 512, bm, bn, As, Bs, acc);
        #pragma unroll
        for (int i = 0; i < 4; ++i)
            #pragma unroll
            for (int j = 0; j < 4; ++j)
                fore[(size_t)(bm + ty * 4 + i) * 512 + bn + tx * 4 + j] =
                    acc[i][j] + beff[bn + tx * 4 + j];
    } else {                               // Gf tile: 256 total = 64 x 4
        const int g = bt - fore_cnt;
        const int bm = (g >> 2) * 64, bn = (g & 3) * 64;
        float acc[4][4] = {};
        gemm_tile_acc<true>(x, Wg, 512, 256, bm, bn, As, Bs, acc);
        #pragma unroll
        for (int i = 0; i < 4; ++i)
            #pragma unroll
            for (int j = 0; j < 4; ++j)
                Gf[(size_t)(bm + ty * 4 + i) * 256 + bn + tx * 4 + j] = acc[i][j];
    }
}

// ---------------------------------------------------------------------------
// finish: blocks [0,64) forecast cells (exact); [64,128) progress broadcast
// ---------------------------------------------------------------------------
__global__ __launch_bounds__(256) void finish_kernel(
    const float* __restrict__ Gf, const float* __restrict__ bf2,
    const float* __restrict__ Whh, const float* __restrict__ bih,
    const float* __restrict__ bhh, const float* __restrict__ Whr,
    const float* __restrict__ c_hist, const float* __restrict__ p,
    float* __restrict__ out)
{
    constexpr int S = 4096, BS = 4 * 4096;
    const int bid = blockIdx.x;
    if (bid < 64) {
        const int w = threadIdx.x >> 6, j = threadIdx.x & 63;
        const float bi0 = bf2[j]       + bih[j]       + bhh[j];
        const float bi1 = bf2[64 + j]  + bih[64 + j]  + bhh[64 + j];
        const float bi2 = bf2[128 + j] + bih[128 + j] + bhh[128 + j];
        const float bi3 = bf2[192 + j] + bih[192 + j] + bhh[192 + j];
        for (int o = 0; o < 16; ++o) {
            const int t = bid * 64 + w * 16 + o;
            const float h2 = p[t];
            const float c2 = c_hist[(size_t)t * 64 + j];
            const float* G = Gf + (size_t)t * 256;
            const float gi = G[j]       + bi0 + Whh[j] * h2;
            const float gf = G[64 + j]  + bi1 + Whh[64 + j] * h2;
            const float gg = G[128 + j] + bi2 + Whh[128 + j] * h2;
            const float go = G[192 + j] + bi3 + Whh[192 + j] * h2;
            const float cf = fsig(gf) * c2 + fsig(gi) * ftanh(gg);
            float hv = fsig(go) * ftanh(cf) * Whr[j];
            hv = dpp_sum64_lane63(hv);
            if (j == 63) {
                out[BS + 0 * S + t] = hv;
                out[BS + 1 * S + t] = hv;
                out[BS + 2 * S + t] = hv;
                out[BS + 3 * S + t] = hv;
            }
        }
    } else {
        const int i = (bid - 64) * 256 + threadIdx.x;
        out[i] = p[i & (S - 1)];
    }
}

extern "C" void kernel_launch(void* const* d_in, const int* in_sizes, int n_in,
                              void* d_out, int out_size, void* d_ws, size_t ws_size,
                              hipStream_t stream) {
    const float* x   = (const float*)d_in[0];
    const float* W1  = (const float*)d_in[1];
    const float* b1  = (const float*)d_in[2];
    const float* W2  = (const float*)d_in[3];
    const float* b2  = (const float*)d_in[4];
    const float* Wih = (const float*)d_in[5];
    const float* Whh = (const float*)d_in[6];
    const float* bih = (const float*)d_in[7];
    const float* bhh = (const float*)d_in[8];
    const float* Whr = (const float*)d_in[9];
    float* out = (float*)d_out;

    constexpr int Bb = 4, S = 4096;
    const int M = Bb * S; // 16384

    float* ws     = (float*)d_ws;
    float* Weff   = ws;                       // 512*512
    float* beff   = Weff + 512 * 512;         // 512
    float* Gx     = beff + 512;               // 4096*256 (RAW pre-activations)
    float* Gf     = Gx + S * 256;             // 4096*256
    float* c_hist = Gf + S * 256;             // 4096*64
    float* p      = c_hist + S * 64;          // 4096
    float* Wg     = p + S;                    // 256*512
    float* bf2    = Wg + 256 * 512;           // 256
    float* Pp     = bf2 + 256;                // 64*64
    float* Qq     = Pp + 4096;                // 64*64
    float* h0     = Qq + 4096;                // 4096
    float* h1     = h0 + 4096;                // 4096

    float* fore = out + 2 * M;                // (16384,512) region of d_out

    // 1) Weff/beff/Gx
    prep_kernel<<<328, 256, 0, stream>>>(
        x, W1, b1, W2, b2, Wih, bih, bhh, Weff, beff, Gx);

    // 2) Wg = Wih@Weff, bf2 = Wih@beff
    wg_kernel<<<33, 256, 0, stream>>>(Wih, Weff, beff, Wg, bf2);

    // 3) fixed-point iterations (K=3), each A/B kernel carries a slice of the
    //    fore GEMM (2048 tiles total) so the GPU stays busy. Gf rides on K1.
    // K1: A it0
    fused_kernel<<<16 + 342 + 256, 256, 0, stream>>>(
        0, 1, 0, x, Weff, beff, Wg, Gx, Whh, Whr,
        h0, h0, Pp, Qq, c_hist, p, fore, Gf, 0, 342);
    // K2: B it0 -> h0
    fused_kernel<<<16 + 342, 256, 0, stream>>>(
        1, 1, 0, x, Weff, beff, Wg, Gx, Whh, Whr,
        h0, h0, Pp, Qq, c_hist, p, fore, Gf, 342, 342);
    // K3: A it1 (reads h0)
    fused_kernel<<<16 + 341, 256, 0, stream>>>(
        0, 0, 0, x, Weff, beff, Wg, Gx, Whh, Whr,
        h0, h1, Pp, Qq, c_hist, p, fore, Gf, 684, 341);
    // K4: B it1 (reads h0) -> h1
    fused_kernel<<<16 + 341, 256, 0, stream>>>(
        1, 0, 0, x, Weff, beff, Wg, Gx, Whh, Whr,
        h0, h1, Pp, Qq, c_hist, p, fore, Gf, 1025, 341);
    // K5: A it2 (reads h1)
    fused_kernel<<<16 + 341, 256, 0, stream>>>(
        0, 0, 0, x, Weff, beff, Wg, Gx, Whh, Whr,
        h1, h0, Pp, Qq, c_hist, p, fore, Gf, 1366, 341);
    // K6: B it2 (reads h1) -> h0, + store c_hist & p (last=1)
    fused_kernel<<<16 + 341, 256, 0, stream>>>(
        1, 0, 1, x, Weff, beff, Wg, Gx, Whh, Whr,
        h1, h0, Pp, Qq, c_hist, p, fore, Gf, 1707, 341);

    // 4) forecast cells + output broadcasts
    finish_kernel<<<128, 256, 0, stream>>>(
        Gf, bf2, Whh, bih, bhh, Whr, c_hist, p, out);
}

// Round 11
// 231.480 us; speedup vs baseline: 3.1166x; 1.8959x over previous
//
#include <hip/hip_runtime.h>
#include <hip/hip_bf16.h>

// B=4, S=4096, D=512, FH=2048, H=64
// outputs: progress (B*S) ++ forecast (B*S) ++ fore (B*S*D), all f32
//
// Structure:
//   conv:  bf16 conversions (xb, W2b, W1t, Wihb) + gxbias
//   prep:  Weffb = bf16(W2@W1) [MFMA], beff = W2@b1+b2 [f32], Gx [MFMA]
//   4 x fused: {A|B} fixed-point iterations (K=2) + MFMA fore/Gf tiles
//   finish: forecast cells + broadcasts

#if __has_builtin(__builtin_amdgcn_exp2f)
__device__ __forceinline__ float EXP2(float x) { return __builtin_amdgcn_exp2f(x); }
#else
__device__ __forceinline__ float EXP2(float x) { return __expf(x * 0.6931471805599453f); }
#endif
#if __has_builtin(__builtin_amdgcn_rcpf)
__device__ __forceinline__ float RCPF(float x) { return __builtin_amdgcn_rcpf(x); }
#else
__device__ __forceinline__ float RCPF(float x) { return 1.0f / x; }
#endif

constexpr float L2E  = 1.4426950408889634f;
constexpr float L2E2 = 2.8853900817779268f;

__device__ __forceinline__ float fsig(float x) { return 1.0f / (1.0f + __expf(-x)); }
__device__ __forceinline__ float ftanh(float x) { return 1.0f - 2.0f / (1.0f + __expf(2.0f * x)); }
__device__ __forceinline__ float sig_f(float x)  { return RCPF(1.0f + EXP2(-L2E * x)); }
__device__ __forceinline__ float tanh_f(float x) { return fmaf(-2.0f, RCPF(1.0f + EXP2(L2E2 * x)), 1.0f); }

template<int CTRL>
__device__ __forceinline__ float dppadd(float x) {
    return x + __int_as_float(__builtin_amdgcn_update_dpp(
        0, __float_as_int(x), CTRL, 0xf, 0xf, true));
}
__device__ __forceinline__ float dpp_sum64_lane63(float x) {
    x = dppadd<0x111>(x); x = dppadd<0x112>(x); x = dppadd<0x114>(x);
    x = dppadd<0x118>(x); x = dppadd<0x142>(x); x = dppadd<0x143>(x);
    return x;
}
__device__ __forceinline__ float readlane63(float x) {
    return __int_as_float(__builtin_amdgcn_readlane(__float_as_int(x), 63));
}
__device__ __forceinline__ float readlane_s(float x, int s) {
    return __int_as_float(__builtin_amdgcn_readlane(__float_as_int(x), s));
}

using bf16x8 = __attribute__((ext_vector_type(8))) __bf16;
using f32x4  = __attribute__((ext_vector_type(4))) float;

// ---------------------------------------------------------------------------
// MFMA 64x64 tile (4 waves, wave w = rows bm+w*16, cols bn..bn+63), K%32==0.
// A: [M][lda] bf16 row-major (k contiguous). B: [N][ldb] bf16 row-major
// (k contiguous) = B^T layout. mfma_f32_16x16x32_bf16:
//   A-frag lane l: row = l&15, k = (l>>4)*8 + j (8 contiguous bf16)
//   B-frag lane l: col = l&15, k = (l>>4)*8 + j
//   D      lane l: col = l&15, row = (l>>4)*4 + i      [guide §3, verified]
// ---------------------------------------------------------------------------
__device__ __forceinline__ void mfma_tile64(
    const __hip_bfloat16* __restrict__ A, int lda,
    const __hip_bfloat16* __restrict__ B, int ldb,
    int K, int bm, int bn,
    const float* __restrict__ bias,                 // nullptr -> none
    float* __restrict__ Cf, int ldc,                // nullptr -> skip
    __hip_bfloat16* __restrict__ Cb)                // nullptr -> skip
{
    const int w    = threadIdx.x >> 6;
    const int lane = threadIdx.x & 63;
    const int rc   = lane & 15;
    const int kg   = lane >> 4;
    const __hip_bfloat16* ap = A + (size_t)(bm + w * 16 + rc) * lda + kg * 8;
    const __hip_bfloat16* bp = B + (size_t)(bn + rc) * ldb + kg * 8;

    f32x4 acc0{0.f,0.f,0.f,0.f}, acc1{0.f,0.f,0.f,0.f};
    f32x4 acc2{0.f,0.f,0.f,0.f}, acc3{0.f,0.f,0.f,0.f};
    #pragma unroll 4
    for (int k0 = 0; k0 < K; k0 += 32) {
        const bf16x8 a  = *reinterpret_cast<const bf16x8*>(ap + k0);
        const bf16x8 b0 = *reinterpret_cast<const bf16x8*>(bp + k0);
        const bf16x8 b1 = *reinterpret_cast<const bf16x8*>(bp + (size_t)16 * ldb + k0);
        const bf16x8 b2 = *reinterpret_cast<const bf16x8*>(bp + (size_t)32 * ldb + k0);
        const bf16x8 b3 = *reinterpret_cast<const bf16x8*>(bp + (size_t)48 * ldb + k0);
        acc0 = __builtin_amdgcn_mfma_f32_16x16x32_bf16(a, b0, acc0, 0, 0, 0);
        acc1 = __builtin_amdgcn_mfma_f32_16x16x32_bf16(a, b1, acc1, 0, 0, 0);
        acc2 = __builtin_amdgcn_mfma_f32_16x16x32_bf16(a, b2, acc2, 0, 0, 0);
        acc3 = __builtin_amdgcn_mfma_f32_16x16x32_bf16(a, b3, acc3, 0, 0, 0);
    }
    const int row0 = bm + w * 16 + (lane >> 4) * 4;
    const int col0 = bn + (lane & 15);
    #pragma unroll
    for (int ct = 0; ct < 4; ++ct) {
        const f32x4 av = (ct == 0) ? acc0 : (ct == 1) ? acc1 : (ct == 2) ? acc2 : acc3;
        const int col = col0 + ct * 16;
        const float bb = bias ? bias[col] : 0.0f;
        #pragma unroll
        for (int i = 0; i < 4; ++i) {
            const float v = av[i] + bb;
            const size_t off = (size_t)(row0 + i) * ldc + col;
            if (Cf) Cf[off] = v;
            if (Cb) Cb[off] = __float2bfloat16(v);
        }
    }
}

// ---------------------------------------------------------------------------
// conv: [0,8192) xb | [8192,9216) W2b | [9216,10240) W1t (transpose) |
//       [10240,10368) Wihb | 10368 gxbias
// ---------------------------------------------------------------------------
__global__ __launch_bounds__(256) void conv_kernel(
    const float* __restrict__ x, const float* __restrict__ W2,
    const float* __restrict__ W1, const float* __restrict__ Wih,
    const float* __restrict__ bih, const float* __restrict__ bhh,
    __hip_bfloat16* __restrict__ xb, __hip_bfloat16* __restrict__ W2b,
    __hip_bfloat16* __restrict__ W1t, __hip_bfloat16* __restrict__ Wihb,
    float* __restrict__ gxbias)
{
    const int bid = blockIdx.x, tid = threadIdx.x;
    if (bid < 8192) {
        const size_t i = ((size_t)bid * 256 + tid) * 4;
        const float4 v = *reinterpret_cast<const float4*>(x + i);
        __hip_bfloat16 o[4] = {__float2bfloat16(v.x), __float2bfloat16(v.y),
                               __float2bfloat16(v.z), __float2bfloat16(v.w)};
        *reinterpret_cast<ushort4*>(xb + i) = *reinterpret_cast<const ushort4*>(o);
    } else if (bid < 9216) {
        const size_t i = ((size_t)(bid - 8192) * 256 + tid) * 4;
        const float4 v = *reinterpret_cast<const float4*>(W2 + i);
        __hip_bfloat16 o[4] = {__float2bfloat16(v.x), __float2bfloat16(v.y),
                               __float2bfloat16(v.z), __float2bfloat16(v.w)};
        *reinterpret_cast<ushort4*>(W2b + i) = *reinterpret_cast<const ushort4*>(o);
    } else if (bid < 10240) {
        const size_t o = ((size_t)(bid - 9216) * 256 + tid) * 4; // c*2048 + k0
        const int c = (int)(o >> 11), k0 = (int)(o & 2047);
        __hip_bfloat16 t[4];
        #pragma unroll
        for (int u = 0; u < 4; ++u)
            t[u] = __float2bfloat16(W1[(size_t)(k0 + u) * 512 + c]);
        *reinterpret_cast<ushort4*>(W1t + o) = *reinterpret_cast<const ushort4*>(t);
    } else if (bid < 10368) {
        const size_t i = ((size_t)(bid - 10240) * 256 + tid) * 4;
        const float4 v = *reinterpret_cast<const float4*>(Wih + i);
        __hip_bfloat16 o[4] = {__float2bfloat16(v.x), __float2bfloat16(v.y),
                               __float2bfloat16(v.z), __float2bfloat16(v.w)};
        *reinterpret_cast<ushort4*>(Wihb + i) = *reinterpret_cast<const ushort4*>(o);
    } else {
        gxbias[tid] = bih[tid] + bhh[tid];
    }
}

// ---------------------------------------------------------------------------
// prep: [0,64) Weffb = bf16(W2b@W1t^T) MFMA K=2048 ; [64,72) beff f32 ;
//       [72,328) Gx = xb@Wihb^T + gxbias (f32 out) MFMA
// ---------------------------------------------------------------------------
__global__ __launch_bounds__(256) void prep_kernel(
    const float* __restrict__ W2, const float* __restrict__ b1,
    const float* __restrict__ b2,
    const __hip_bfloat16* __restrict__ W2b, const __hip_bfloat16* __restrict__ W1t,
    const __hip_bfloat16* __restrict__ xb, const __hip_bfloat16* __restrict__ Wihb,
    const float* __restrict__ gxbias,
    __hip_bfloat16* __restrict__ Weffb, float* __restrict__ beff,
    float* __restrict__ Gx)
{
    const int bid = blockIdx.x;
    if (bid < 64) {
        const int bm = (bid >> 3) * 64, bn = (bid & 7) * 64;
        mfma_tile64(W2b, 2048, W1t, 2048, 2048, bm, bn, nullptr,
                    nullptr, 512, Weffb);
    } else if (bid < 72) {
        const int w = threadIdx.x >> 6, j = threadIdx.x & 63;
        const int base = (bid - 64) * 64 + w * 16;
        for (int o = 0; o < 16; ++o) {
            const int i = base + o;
            float s = 0.0f;
            #pragma unroll
            for (int m = 0; m < 32; ++m)
                s = fmaf(W2[(size_t)i * 2048 + j + 64 * m], b1[j + 64 * m], s);
            s = dpp_sum64_lane63(s);
            if (j == 63) beff[i] = s + b2[i];
        }
    } else {
        const int b = bid - 72;
        const int bm = (b >> 2) * 64, bn = (b & 3) * 64;
        mfma_tile64(xb, 512, Wihb, 512, 512, bm, bn, gxbias,
                    Gx, 256, nullptr);
    }
}

// ---------------------------------------------------------------------------
// fused: [0,16) fixed-point phase (64 chunk-waves);
//        [16,16+fore_cnt) fore MFMA tiles; then gf_cnt Gf MFMA tiles.
// ---------------------------------------------------------------------------
__global__ __launch_bounds__(256) void fused_kernel(
    int phase, int first, int last, int copyb,
    int fore_base, int fore_cnt,
    const __hip_bfloat16* __restrict__ xb, const __hip_bfloat16* __restrict__ Weffb,
    const __hip_bfloat16* __restrict__ Wihb, const __hip_bfloat16* __restrict__ foreb_in,
    const float* __restrict__ beff, const float* __restrict__ Gx,
    const float* __restrict__ Whh, const float* __restrict__ Whr,
    const float* __restrict__ hprev, float* __restrict__ hnext,
    float* __restrict__ P, float* __restrict__ Q,
    float* __restrict__ c_hist, float* __restrict__ p,
    float* __restrict__ fore, __hip_bfloat16* __restrict__ foreb_out,
    float* __restrict__ Gf)
{
    if (blockIdx.x < 16) {
        const int chunk = blockIdx.x * 4 + (threadIdx.x >> 6);  // 0..63
        const int j = threadIdx.x & 63;
        const float wi = Whh[j], wf = Whh[64 + j];
        const float wg2 = Whh[128 + j], wo = Whh[192 + j];
        const float* ab = Gx + (size_t)chunk * 64 * 256 + j;

        float hp = 0.0f;
        if (!first) {
            const int idx = chunk * 64 - 1 + j;
            hp = (idx >= 0) ? hprev[idx] : 0.0f;
        }

        if (phase == 0) {
            float Pv = 1.0f, Qv = 0.0f;
            #pragma unroll 8
            for (int s = 0; s < 64; ++s) {
                const float hs = first ? 0.0f : readlane_s(hp, s);
                const float ai = ab[s * 256]       + wi  * hs;
                const float af = ab[s * 256 + 64]  + wf  * hs;
                const float ag = ab[s * 256 + 128] + wg2 * hs;
                const float si = sig_f(ai);
                const float sf = sig_f(af);
                const float tg = tanh_f(ag);
                Pv = sf * Pv;
                Qv = fmaf(sf, Qv, si * tg);
            }
            P[chunk * 64 + j] = Pv;
            Q[chunk * 64 + j] = Qv;
        } else {
            const float whr = Whr[j];
            float c = 0.0f;
            #pragma unroll 8
            for (int m = 0; m < chunk; ++m)
                c = fmaf(P[m * 64 + j], c, Q[m * 64 + j]);
            float vp = 0.0f;
            #pragma unroll 4
            for (int s = 0; s < 64; ++s) {
                const float hs = first ? 0.0f : readlane_s(hp, s);
                const float ai = ab[s * 256]       + wi  * hs;
                const float af = ab[s * 256 + 64]  + wf  * hs;
                const float ag = ab[s * 256 + 128] + wg2 * hs;
                const float ao = ab[s * 256 + 192] + wo  * hs;
                const float si = sig_f(ai);
                const float sf = sig_f(af);
                const float tg = tanh_f(ag);
                const float so = sig_f(ao);
                c = fmaf(sf, c, si * tg);
                if (last) c_hist[(size_t)(chunk * 64 + s) * 64 + j] = c;
                const float tc = tanh_f(c);
                float hv = tc * (so * whr);
                hv = dpp_sum64_lane63(hv);
                const float hn = readlane63(hv);
                vp = (j == s) ? hn : vp;
            }
            hnext[chunk * 64 + j] = vp;
            if (last) p[chunk * 64 + j] = vp;
        }
        return;
    }

    const int bt = blockIdx.x - 16;
    if (bt < fore_cnt) {
        const int tile = fore_base + bt;
        const int bm = (tile >> 3) * 64, bn = (tile & 7) * 64;
        mfma_tile64(xb, 512, Weffb, 512, 512, bm, bn, beff,
                    fore, 512, copyb ? foreb_out : nullptr);
    } else {
        const int g = bt - fore_cnt;                 // Gf: 256 tiles (64 x 4)
        const int bm = (g >> 2) * 64, bn = (g & 3) * 64;
        mfma_tile64(foreb_in, 512, Wihb, 512, 512, bm, bn, nullptr,
                    Gf, 256, nullptr);
    }
}

// ---------------------------------------------------------------------------
// finish: [0,64) forecast cells (exact); [64,128) progress broadcast
// ---------------------------------------------------------------------------
__global__ __launch_bounds__(256) void finish_kernel(
    const float* __restrict__ Gf,
    const float* __restrict__ Whh, const float* __restrict__ bih,
    const float* __restrict__ bhh, const float* __restrict__ Whr,
    const float* __restrict__ c_hist, const float* __restrict__ p,
    float* __restrict__ out)
{
    constexpr int S = 4096, BS = 4 * 4096;
    const int bid = blockIdx.x;
    if (bid < 64) {
        const int w = threadIdx.x >> 6, j = threadIdx.x & 63;
        const float bi0 = bih[j]       + bhh[j];
        const float bi1 = bih[64 + j]  + bhh[64 + j];
        const float bi2 = bih[128 + j] + bhh[128 + j];
        const float bi3 = bih[192 + j] + bhh[192 + j];
        for (int o = 0; o < 16; ++o) {
            const int t = bid * 64 + w * 16 + o;
            const float h2 = p[t];
            const float c2 = c_hist[(size_t)t * 64 + j];
            const float* G = Gf + (size_t)t * 256;
            const float gi = G[j]       + bi0 + Whh[j] * h2;
            const float gf = G[64 + j]  + bi1 + Whh[64 + j] * h2;
            const float gg = G[128 + j] + bi2 + Whh[128 + j] * h2;
            const float go = G[192 + j] + bi3 + Whh[192 + j] * h2;
            const float cf = fsig(gf) * c2 + fsig(gi) * ftanh(gg);
            float hv = fsig(go) * ftanh(cf) * Whr[j];
            hv = dpp_sum64_lane63(hv);
            if (j == 63) {
                out[BS + 0 * S + t] = hv;
                out[BS + 1 * S + t] = hv;
                out[BS + 2 * S + t] = hv;
                out[BS + 3 * S + t] = hv;
            }
        }
    } else {
        const int i = (bid - 64) * 256 + threadIdx.x;
        out[i] = p[i & (S - 1)];
    }
}

extern "C" void kernel_launch(void* const* d_in, const int* in_sizes, int n_in,
                              void* d_out, int out_size, void* d_ws, size_t ws_size,
                              hipStream_t stream) {
    const float* x   = (const float*)d_in[0];
    const float* W1  = (const float*)d_in[1];
    const float* b1  = (const float*)d_in[2];
    const float* W2  = (const float*)d_in[3];
    const float* b2  = (const float*)d_in[4];
    const float* Wih = (const float*)d_in[5];
    const float* Whh = (const float*)d_in[6];
    const float* bih = (const float*)d_in[7];
    const float* bhh = (const float*)d_in[8];
    const float* Whr = (const float*)d_in[9];
    float* out = (float*)d_out;

    constexpr int Bb = 4, S = 4096;
    const int M = Bb * S; // 16384

    // workspace layout
    float* ws      = (float*)d_ws;
    float* beff    = ws;                         // 512
    float* gxbias  = beff + 512;                 // 256
    float* Gx      = gxbias + 256;               // 4096*256
    float* Gf      = Gx + S * 256;               // 4096*256
    float* c_hist  = Gf + S * 256;               // 4096*64
    float* p       = c_hist + S * 64;            // 4096
    float* Pp      = p + S;                      // 4096
    float* Qq      = Pp + S;                     // 4096
    float* h0      = Qq + S;                     // 4096
    float* h1      = h0 + S;                     // 4096
    __hip_bfloat16* xb    = (__hip_bfloat16*)(h1 + S);   // 16384*512
    __hip_bfloat16* W2b   = xb + (size_t)M * 512;        // 512*2048
    __hip_bfloat16* W1t   = W2b + 512 * 2048;            // 512*2048 (transposed)
    __hip_bfloat16* Wihb  = W1t + 512 * 2048;            // 256*512
    __hip_bfloat16* Weffb = Wihb + 256 * 512;            // 512*512
    __hip_bfloat16* foreb = Weffb + 512 * 512;           // 4096*512

    float* fore = out + 2 * M;                   // (16384,512) region of d_out

    // 1) conversions
    conv_kernel<<<10369, 256, 0, stream>>>(
        x, W2, W1, Wih, bih, bhh, xb, W2b, W1t, Wihb, gxbias);

    // 2) Weffb (MFMA) + beff + Gx (MFMA)
    prep_kernel<<<328, 256, 0, stream>>>(
        W2, b1, b2, W2b, W1t, xb, Wihb, gxbias, Weffb, beff, Gx);

    // 3) fixed-point (K=2): A0, B0, A1, B1(last). fore tiles 512/kernel;
    //    K1's tiles are rows 0..4095 (bf16 copy -> foreb); Gf rides on K2.
    fused_kernel<<<16 + 512, 256, 0, stream>>>(
        0, 1, 0, 1, 0, 512, xb, Weffb, Wihb, foreb, beff, Gx, Whh, Whr,
        h0, h0, Pp, Qq, c_hist, p, fore, foreb, Gf);
    fused_kernel<<<16 + 512 + 256, 256, 0, stream>>>(
        1, 1, 0, 0, 512, 512, xb, Weffb, Wihb, foreb, beff, Gx, Whh, Whr,
        h0, h0, Pp, Qq, c_hist, p, fore, foreb, Gf);
    fused_kernel<<<16 + 512, 256, 0, stream>>>(
        0, 0, 0, 0, 1024, 512, xb, Weffb, Wihb, foreb, beff, Gx, Whh, Whr,
        h0, h1, Pp, Qq, c_hist, p, fore, foreb, Gf);
    fused_kernel<<<16 + 512, 256, 0, stream>>>(
        1, 0, 1, 0, 1536, 512, xb, Weffb, Wihb, foreb, beff, Gx, Whh, Whr,
        h0, h1, Pp, Qq, c_hist, p, fore, foreb, Gf);

    // 4) forecast cells + output broadcasts
    finish_kernel<<<128, 256, 0, stream>>>(
        Gf, Whh, bih, bhh, Whr, c_hist, p, out);
}

// Round 12
// 201.686 us; speedup vs baseline: 3.5770x; 1.1477x over previous
//
#include <hip/hip_runtime.h>
#include <hip/hip_bf16.h>

// B=4, S=4096, D=512, FH=2048, H=64
// outputs: progress (B*S) ++ forecast (B*S) ++ fore (B*S*D), all f32
//
// Structure:
//   conv:  bf16 conversions (xb, W2b, W1t, Wihb) + gxbias
//   prep:  Weffb = bf16(W2@W1) [MFMA], beff = W2@b1+b2, Gx = act-preacts [MFMA]
//   K1: fixed-point A0 + ALL 1024 fore MFMA tiles (bf16 copy of rows 0-4095)
//   K2: fixed-point B0 + 128 Gf MFMA tiles
//   K3: fixed-point A1 (scan only)
//   K4: fixed-point B1 (scan only, stores c_hist/p)
//   finish: forecast cells + broadcasts

#if __has_builtin(__builtin_amdgcn_exp2f)
__device__ __forceinline__ float EXP2(float x) { return __builtin_amdgcn_exp2f(x); }
#else
__device__ __forceinline__ float EXP2(float x) { return __expf(x * 0.6931471805599453f); }
#endif
#if __has_builtin(__builtin_amdgcn_rcpf)
__device__ __forceinline__ float RCPF(float x) { return __builtin_amdgcn_rcpf(x); }
#else
__device__ __forceinline__ float RCPF(float x) { return 1.0f / x; }
#endif

constexpr float L2E  = 1.4426950408889634f;
constexpr float L2E2 = 2.8853900817779268f;

__device__ __forceinline__ float fsig(float x) { return 1.0f / (1.0f + __expf(-x)); }
__device__ __forceinline__ float ftanh(float x) { return 1.0f - 2.0f / (1.0f + __expf(2.0f * x)); }
__device__ __forceinline__ float sig_f(float x)  { return RCPF(1.0f + EXP2(-L2E * x)); }
__device__ __forceinline__ float tanh_f(float x) { return fmaf(-2.0f, RCPF(1.0f + EXP2(L2E2 * x)), 1.0f); }

template<int CTRL>
__device__ __forceinline__ float dppadd(float x) {
    return x + __int_as_float(__builtin_amdgcn_update_dpp(
        0, __float_as_int(x), CTRL, 0xf, 0xf, true));
}
__device__ __forceinline__ float dpp_sum64_lane63(float x) {
    x = dppadd<0x111>(x); x = dppadd<0x112>(x); x = dppadd<0x114>(x);
    x = dppadd<0x118>(x); x = dppadd<0x142>(x); x = dppadd<0x143>(x);
    return x;
}
__device__ __forceinline__ float readlane63(float x) {
    return __int_as_float(__builtin_amdgcn_readlane(__float_as_int(x), 63));
}
__device__ __forceinline__ float readlane_s(float x, int s) {
    return __int_as_float(__builtin_amdgcn_readlane(__float_as_int(x), s));
}

using bf16x8 = __attribute__((ext_vector_type(8))) __bf16;
using f32x4  = __attribute__((ext_vector_type(4))) float;

// ---------------------------------------------------------------------------
// MFMA 128x64 tile (4 waves; wave w covers rows {bm+w*16, bm+64+w*16}).
// A: [M][lda] bf16 row-major (k contiguous). B: [N][ldb] bf16 (B^T layout).
// Register double-buffered k-loop: 6 loads + 8 MFMA per k-step of 32.
// mfma_f32_16x16x32_bf16 layouts (verified round 11):
//   A/B-frag lane l: row/col = l&15, k = (l>>4)*8 + j
//   D        lane l: col = l&15, row = (l>>4)*4 + i
// ---------------------------------------------------------------------------
__device__ __forceinline__ void mfma_tile128(
    const __hip_bfloat16* __restrict__ A, int lda,
    const __hip_bfloat16* __restrict__ B, int ldb,
    int K, int bm, int bn,
    const float* __restrict__ bias,                 // nullptr -> none
    float* __restrict__ Cf, int ldc,                // nullptr -> skip
    __hip_bfloat16* __restrict__ Cb)                // nullptr -> skip (same ldc)
{
    const int w    = threadIdx.x >> 6;
    const int lane = threadIdx.x & 63;
    const int rc   = lane & 15;
    const int kg   = lane >> 4;
    const __hip_bfloat16* ap0 = A + (size_t)(bm + w * 16 + rc) * lda + kg * 8;
    const __hip_bfloat16* ap1 = ap0 + (size_t)64 * lda;
    const __hip_bfloat16* bp0 = B + (size_t)(bn + rc) * ldb + kg * 8;
    const __hip_bfloat16* bp1 = bp0 + (size_t)16 * ldb;
    const __hip_bfloat16* bp2 = bp0 + (size_t)32 * ldb;
    const __hip_bfloat16* bp3 = bp0 + (size_t)48 * ldb;

#define LD8(P) (*reinterpret_cast<const bf16x8*>(P))
    const f32x4 z{0.f, 0.f, 0.f, 0.f};
    f32x4 c00 = z, c01 = z, c02 = z, c03 = z;
    f32x4 c10 = z, c11 = z, c12 = z, c13 = z;

    bf16x8 a0 = LD8(ap0), a1 = LD8(ap1);
    bf16x8 b0 = LD8(bp0), b1 = LD8(bp1), b2 = LD8(bp2), b3 = LD8(bp3);
    const int nst = K >> 5;
    for (int s = 1; s <= nst; ++s) {
        bf16x8 a0n = a0, a1n = a1, b0n = b0, b1n = b1, b2n = b2, b3n = b3;
        if (s < nst) {
            const int k0 = s << 5;
            a0n = LD8(ap0 + k0); a1n = LD8(ap1 + k0);
            b0n = LD8(bp0 + k0); b1n = LD8(bp1 + k0);
            b2n = LD8(bp2 + k0); b3n = LD8(bp3 + k0);
        }
        c00 = __builtin_amdgcn_mfma_f32_16x16x32_bf16(a0, b0, c00, 0, 0, 0);
        c01 = __builtin_amdgcn_mfma_f32_16x16x32_bf16(a0, b1, c01, 0, 0, 0);
        c02 = __builtin_amdgcn_mfma_f32_16x16x32_bf16(a0, b2, c02, 0, 0, 0);
        c03 = __builtin_amdgcn_mfma_f32_16x16x32_bf16(a0, b3, c03, 0, 0, 0);
        c10 = __builtin_amdgcn_mfma_f32_16x16x32_bf16(a1, b0, c10, 0, 0, 0);
        c11 = __builtin_amdgcn_mfma_f32_16x16x32_bf16(a1, b1, c11, 0, 0, 0);
        c12 = __builtin_amdgcn_mfma_f32_16x16x32_bf16(a1, b2, c12, 0, 0, 0);
        c13 = __builtin_amdgcn_mfma_f32_16x16x32_bf16(a1, b3, c13, 0, 0, 0);
        a0 = a0n; a1 = a1n; b0 = b0n; b1 = b1n; b2 = b2n; b3 = b3n;
    }
#undef LD8

    const int row0 = bm + w * 16 + kg * 4;
    const int colb = bn + rc;
#define EPI(ACC, HOFF, CT) {                                                  \
        const int col = colb + (CT) * 16;                                     \
        const float bb = bias ? bias[col] : 0.0f;                             \
        _Pragma("unroll")                                                     \
        for (int i = 0; i < 4; ++i) {                                         \
            const float v = (ACC)[i] + bb;                                    \
            const size_t off = (size_t)(row0 + (HOFF) + i) * ldc + col;       \
            if (Cf) Cf[off] = v;                                              \
            if (Cb) Cb[off] = __float2bfloat16(v);                            \
        }}
    EPI(c00, 0, 0)  EPI(c01, 0, 1)  EPI(c02, 0, 2)  EPI(c03, 0, 3)
    EPI(c10, 64, 0) EPI(c11, 64, 1) EPI(c12, 64, 2) EPI(c13, 64, 3)
#undef EPI
}

// ---------------------------------------------------------------------------
// conv: [0,8192) xb | [8192,9216) W2b | [9216,10240) W1t (transpose) |
//       [10240,10368) Wihb | 10368 gxbias
// ---------------------------------------------------------------------------
__global__ __launch_bounds__(256) void conv_kernel(
    const float* __restrict__ x, const float* __restrict__ W2,
    const float* __restrict__ W1, const float* __restrict__ Wih,
    const float* __restrict__ bih, const float* __restrict__ bhh,
    __hip_bfloat16* __restrict__ xb, __hip_bfloat16* __restrict__ W2b,
    __hip_bfloat16* __restrict__ W1t, __hip_bfloat16* __restrict__ Wihb,
    float* __restrict__ gxbias)
{
    const int bid = blockIdx.x, tid = threadIdx.x;
    if (bid < 8192) {
        const size_t i = ((size_t)bid * 256 + tid) * 4;
        const float4 v = *reinterpret_cast<const float4*>(x + i);
        __hip_bfloat16 o[4] = {__float2bfloat16(v.x), __float2bfloat16(v.y),
                               __float2bfloat16(v.z), __float2bfloat16(v.w)};
        *reinterpret_cast<ushort4*>(xb + i) = *reinterpret_cast<const ushort4*>(o);
    } else if (bid < 9216) {
        const size_t i = ((size_t)(bid - 8192) * 256 + tid) * 4;
        const float4 v = *reinterpret_cast<const float4*>(W2 + i);
        __hip_bfloat16 o[4] = {__float2bfloat16(v.x), __float2bfloat16(v.y),
                               __float2bfloat16(v.z), __float2bfloat16(v.w)};
        *reinterpret_cast<ushort4*>(W2b + i) = *reinterpret_cast<const ushort4*>(o);
    } else if (bid < 10240) {
        const size_t o = ((size_t)(bid - 9216) * 256 + tid) * 4; // c*2048 + k0
        const int c = (int)(o >> 11), k0 = (int)(o & 2047);
        __hip_bfloat16 t[4];
        #pragma unroll
        for (int u = 0; u < 4; ++u)
            t[u] = __float2bfloat16(W1[(size_t)(k0 + u) * 512 + c]);
        *reinterpret_cast<ushort4*>(W1t + o) = *reinterpret_cast<const ushort4*>(t);
    } else if (bid < 10368) {
        const size_t i = ((size_t)(bid - 10240) * 256 + tid) * 4;
        const float4 v = *reinterpret_cast<const float4*>(Wih + i);
        __hip_bfloat16 o[4] = {__float2bfloat16(v.x), __float2bfloat16(v.y),
                               __float2bfloat16(v.z), __float2bfloat16(v.w)};
        *reinterpret_cast<ushort4*>(Wihb + i) = *reinterpret_cast<const ushort4*>(o);
    } else {
        gxbias[tid] = bih[tid] + bhh[tid];
    }
}

// ---------------------------------------------------------------------------
// prep: [0,32) Weffb tiles (128x64, K=2048); [32,40) beff f32;
//       [40,168) Gx = xb@Wihb^T + gxbias (128x64, K=512)
// ---------------------------------------------------------------------------
__global__ __launch_bounds__(256) void prep_kernel(
    const float* __restrict__ W2, const float* __restrict__ b1,
    const float* __restrict__ b2,
    const __hip_bfloat16* __restrict__ W2b, const __hip_bfloat16* __restrict__ W1t,
    const __hip_bfloat16* __restrict__ xb, const __hip_bfloat16* __restrict__ Wihb,
    const float* __restrict__ gxbias,
    __hip_bfloat16* __restrict__ Weffb, float* __restrict__ beff,
    float* __restrict__ Gx)
{
    const int bid = blockIdx.x;
    if (bid < 32) {
        const int bm = (bid >> 3) * 128, bn = (bid & 7) * 64;
        mfma_tile128(W2b, 2048, W1t, 2048, 2048, bm, bn, nullptr,
                     nullptr, 512, Weffb);
    } else if (bid < 40) {
        const int w = threadIdx.x >> 6, j = threadIdx.x & 63;
        const int base = (bid - 32) * 64 + w * 16;
        for (int o = 0; o < 16; ++o) {
            const int i = base + o;
            float s = 0.0f;
            #pragma unroll
            for (int m = 0; m < 32; ++m)
                s = fmaf(W2[(size_t)i * 2048 + j + 64 * m], b1[j + 64 * m], s);
            s = dpp_sum64_lane63(s);
            if (j == 63) beff[i] = s + b2[i];
        }
    } else {
        const int b = bid - 40;
        const int bm = (b >> 2) * 128, bn = (b & 3) * 64;
        mfma_tile128(xb, 512, Wihb, 512, 512, bm, bn, gxbias,
                     Gx, 256, nullptr);
    }
}

// ---------------------------------------------------------------------------
// fused: [0,16) fixed-point phase (64 chunk-waves);
//        [16,16+fore_cnt) fore 128x64 MFMA tiles; remaining = Gf tiles.
// ---------------------------------------------------------------------------
__global__ __launch_bounds__(256) void fused_kernel(
    int phase, int first, int last, int copyb,
    int fore_base, int fore_cnt,
    const __hip_bfloat16* __restrict__ xb, const __hip_bfloat16* __restrict__ Weffb,
    const __hip_bfloat16* __restrict__ Wihb, const __hip_bfloat16* __restrict__ foreb_in,
    const float* __restrict__ beff, const float* __restrict__ Gx,
    const float* __restrict__ Whh, const float* __restrict__ Whr,
    const float* __restrict__ hprev, float* __restrict__ hnext,
    float* __restrict__ P, float* __restrict__ Q,
    float* __restrict__ c_hist, float* __restrict__ p,
    float* __restrict__ fore, __hip_bfloat16* __restrict__ foreb_out,
    float* __restrict__ Gf)
{
    if (blockIdx.x < 16) {
        const int chunk = blockIdx.x * 4 + (threadIdx.x >> 6);  // 0..63
        const int j = threadIdx.x & 63;
        const float wi = Whh[j], wf = Whh[64 + j];
        const float wg2 = Whh[128 + j], wo = Whh[192 + j];
        const float* ab = Gx + (size_t)chunk * 64 * 256 + j;

        float hp = 0.0f;
        if (!first) {
            const int idx = chunk * 64 - 1 + j;
            hp = (idx >= 0) ? hprev[idx] : 0.0f;
        }

        if (phase == 0) {
            float Pv = 1.0f, Qv = 0.0f;
            #pragma unroll 8
            for (int s = 0; s < 64; ++s) {
                const float hs = first ? 0.0f : readlane_s(hp, s);
                const float ai = ab[s * 256]       + wi  * hs;
                const float af = ab[s * 256 + 64]  + wf  * hs;
                const float ag = ab[s * 256 + 128] + wg2 * hs;
                const float si = sig_f(ai);
                const float sf = sig_f(af);
                const float tg = tanh_f(ag);
                Pv = sf * Pv;
                Qv = fmaf(sf, Qv, si * tg);
            }
            P[chunk * 64 + j] = Pv;
            Q[chunk * 64 + j] = Qv;
        } else {
            const float whr = Whr[j];
            float c = 0.0f;
            #pragma unroll 8
            for (int m = 0; m < chunk; ++m)
                c = fmaf(P[m * 64 + j], c, Q[m * 64 + j]);
            float vp = 0.0f;
            #pragma unroll 4
            for (int s = 0; s < 64; ++s) {
                const float hs = first ? 0.0f : readlane_s(hp, s);
                const float ai = ab[s * 256]       + wi  * hs;
                const float af = ab[s * 256 + 64]  + wf  * hs;
                const float ag = ab[s * 256 + 128] + wg2 * hs;
                const float ao = ab[s * 256 + 192] + wo  * hs;
                const float si = sig_f(ai);
                const float sf = sig_f(af);
                const float tg = tanh_f(ag);
                const float so = sig_f(ao);
                c = fmaf(sf, c, si * tg);
                if (last) c_hist[(size_t)(chunk * 64 + s) * 64 + j] = c;
                const float tc = tanh_f(c);
                float hv = tc * (so * whr);
                hv = dpp_sum64_lane63(hv);
                const float hn = readlane63(hv);
                vp = (j == s) ? hn : vp;
            }
            hnext[chunk * 64 + j] = vp;
            if (last) p[chunk * 64 + j] = vp;
        }
        return;
    }

    const int bt = blockIdx.x - 16;
    if (bt < fore_cnt) {                   // fore: 1024 tiles (128 x 8)
        const int tile = fore_base + bt;
        const int bm = (tile >> 3) * 128, bn = (tile & 7) * 64;
        mfma_tile128(xb, 512, Weffb, 512, 512, bm, bn, beff,
                     fore, 512, (copyb && tile < 256) ? foreb_out : nullptr);
    } else {                               // Gf: 128 tiles (32 x 4)
        const int g = bt - fore_cnt;
        const int bm = (g >> 2) * 128, bn = (g & 3) * 64;
        mfma_tile128(foreb_in, 512, Wihb, 512, 512, bm, bn, nullptr,
                     Gf, 256, nullptr);
    }
}

// ---------------------------------------------------------------------------
// finish: [0,64) forecast cells (exact); [64,128) progress broadcast
// ---------------------------------------------------------------------------
__global__ __launch_bounds__(256) void finish_kernel(
    const float* __restrict__ Gf,
    const float* __restrict__ Whh, const float* __restrict__ bih,
    const float* __restrict__ bhh, const float* __restrict__ Whr,
    const float* __restrict__ c_hist, const float* __restrict__ p,
    float* __restrict__ out)
{
    constexpr int S = 4096, BS = 4 * 4096;
    const int bid = blockIdx.x;
    if (bid < 64) {
        const int w = threadIdx.x >> 6, j = threadIdx.x & 63;
        const float bi0 = bih[j]       + bhh[j];
        const float bi1 = bih[64 + j]  + bhh[64 + j];
        const float bi2 = bih[128 + j] + bhh[128 + j];
        const float bi3 = bih[192 + j] + bhh[192 + j];
        for (int o = 0; o < 16; ++o) {
            const int t = bid * 64 + w * 16 + o;
            const float h2 = p[t];
            const float c2 = c_hist[(size_t)t * 64 + j];
            const float* G = Gf + (size_t)t * 256;
            const float gi = G[j]       + bi0 + Whh[j] * h2;
            const float gf = G[64 + j]  + bi1 + Whh[64 + j] * h2;
            const float gg = G[128 + j] + bi2 + Whh[128 + j] * h2;
            const float go = G[192 + j] + bi3 + Whh[192 + j] * h2;
            const float cf = fsig(gf) * c2 + fsig(gi) * ftanh(gg);
            float hv = fsig(go) * ftanh(cf) * Whr[j];
            hv = dpp_sum64_lane63(hv);
            if (j == 63) {
                out[BS + 0 * S + t] = hv;
                out[BS + 1 * S + t] = hv;
                out[BS + 2 * S + t] = hv;
                out[BS + 3 * S + t] = hv;
            }
        }
    } else {
        const int i = (bid - 64) * 256 + threadIdx.x;
        out[i] = p[i & (S - 1)];
    }
}

extern "C" void kernel_launch(void* const* d_in, const int* in_sizes, int n_in,
                              void* d_out, int out_size, void* d_ws, size_t ws_size,
                              hipStream_t stream) {
    const float* x   = (const float*)d_in[0];
    const float* W1  = (const float*)d_in[1];
    const float* b1  = (const float*)d_in[2];
    const float* W2  = (const float*)d_in[3];
    const float* b2  = (const float*)d_in[4];
    const float* Wih = (const float*)d_in[5];
    const float* Whh = (const float*)d_in[6];
    const float* bih = (const float*)d_in[7];
    const float* bhh = (const float*)d_in[8];
    const float* Whr = (const float*)d_in[9];
    float* out = (float*)d_out;

    constexpr int Bb = 4, S = 4096;
    const int M = Bb * S; // 16384

    // workspace layout
    float* ws      = (float*)d_ws;
    float* beff    = ws;                         // 512
    float* gxbias  = beff + 512;                 // 256
    float* Gx      = gxbias + 256;               // 4096*256
    float* Gf      = Gx + S * 256;               // 4096*256
    float* c_hist  = Gf + S * 256;               // 4096*64
    float* p       = c_hist + S * 64;            // 4096
    float* Pp      = p + S;                      // 4096
    float* Qq      = Pp + S;                     // 4096
    float* h0      = Qq + S;                     // 4096
    float* h1      = h0 + S;                     // 4096
    __hip_bfloat16* xb    = (__hip_bfloat16*)(h1 + S);   // 16384*512
    __hip_bfloat16* W2b   = xb + (size_t)M * 512;        // 512*2048
    __hip_bfloat16* W1t   = W2b + 512 * 2048;            // 512*2048 (transposed)
    __hip_bfloat16* Wihb  = W1t + 512 * 2048;            // 256*512
    __hip_bfloat16* Weffb = Wihb + 256 * 512;            // 512*512
    __hip_bfloat16* foreb = Weffb + 512 * 512;           // 4096*512

    float* fore = out + 2 * M;                   // (16384,512) region of d_out

    // 1) conversions
    conv_kernel<<<10369, 256, 0, stream>>>(
        x, W2, W1, Wih, bih, bhh, xb, W2b, W1t, Wihb, gxbias);

    // 2) Weffb (MFMA) + beff + Gx (MFMA)
    prep_kernel<<<168, 256, 0, stream>>>(
        W2, b1, b2, W2b, W1t, xb, Wihb, gxbias, Weffb, beff, Gx);

    // 3) fixed-point (K=2). K1 carries ALL 1024 fore tiles (+bf16 copy of
    //    rows 0-4095); K2 carries the 128 Gf tiles; K3/K4 scan-only.
    fused_kernel<<<16 + 1024, 256, 0, stream>>>(
        0, 1, 0, 1, 0, 1024, xb, Weffb, Wihb, foreb, beff, Gx, Whh, Whr,
        h0, h0, Pp, Qq, c_hist, p, fore, foreb, Gf);
    fused_kernel<<<16 + 128, 256, 0, stream>>>(
        1, 1, 0, 0, 0, 0, xb, Weffb, Wihb, foreb, beff, Gx, Whh, Whr,
        h0, h0, Pp, Qq, c_hist, p, fore, foreb, Gf);
    fused_kernel<<<16, 256, 0, stream>>>(
        0, 0, 0, 0, 0, 0, xb, Weffb, Wihb, foreb, beff, Gx, Whh, Whr,
        h0, h1, Pp, Qq, c_hist, p, fore, foreb, Gf);
    fused_kernel<<<16, 256, 0, stream>>>(
        1, 0, 1, 0, 0, 0, xb, Weffb, Wihb, foreb, beff, Gx, Whh, Whr,
        h0, h1, Pp, Qq, c_hist, p, fore, foreb, Gf);

    // 4) forecast cells + output broadcasts
    finish_kernel<<<128, 256, 0, stream>>>(
        Gf, Whh, bih, bhh, Whr, c_hist, p, out);
}